// Round 3
// baseline (1019.948 us; speedup 1.0000x reference)
//
#include <hip/hip_runtime.h>

typedef unsigned short u16;
typedef unsigned int u32;
typedef unsigned long long u64;
typedef __attribute__((ext_vector_type(8))) short short8;
typedef __attribute__((ext_vector_type(4))) float floatx4;

#define E_ 1024
#define B_ 256
#define M_ 196
#define H_ 8
#define DH_ 128
#define MID_ 64
#define NKROW 50176   // B_*M_

__device__ __forceinline__ u16 f2bf(float f){
  union { float f; u32 u; } v; v.f = f;
  return (u16)((v.u + (((v.u >> 16) & 1u) + 0x7fffu)) >> 16);
}
__device__ __forceinline__ float bf2f(u16 h){
  union { u32 u; float f; } v; v.u = ((u32)h) << 16;
  return v.f;
}
// pack two floats to bf16x2 (round-half-away via +0x8000; a = low element)
__device__ __forceinline__ u32 pack_bf2(float a, float b){
  u32 ua = __float_as_uint(a) + 0x8000u;
  u32 ub = __float_as_uint(b) + 0x8000u;
  return __builtin_amdgcn_perm(ub, ua, 0x07060302);
}
// async global->LDS, 16B/lane; LDS dest = wave-uniform base + lane*16
__device__ __forceinline__ void gl_lds16(const void* g, void* l){
  __builtin_amdgcn_global_load_lds(
      (const __attribute__((address_space(1))) u32*)g,
      (__attribute__((address_space(3))) u32*)l, 16, 0, 0);
}

// ---------------------------------------------------------------------------
// Kernel X: in-place fp32 -> bf16 for the 4 input tensors. 8 rows per block,
// 32 threads/row: read the row's 4KB into regs, barrier, write packed 2KB
// into the row's front half. Writes never leave the row => race-free.
// Resulting layout: bf16 row r at u16-offset r*2048 (row stride 2048 u16).
// ---------------------------------------------------------------------------
__global__ __launch_bounds__(256) void xconv_kernel(
    float* __restrict__ key, float* __restrict__ value2,
    float* __restrict__ query, float* __restrict__ value1)
{
  int gr = blockIdx.x * 8 + (threadIdx.x >> 5);
  int i  = threadIdx.x & 31;
  float* X; int r;
  if (gr < NKROW)               { X = key;    r = gr; }
  else if (gr < 2*NKROW)        { X = value2; r = gr - NKROW; }
  else if (gr < 2*NKROW + B_)   { X = query;  r = gr - 2*NKROW; }
  else                          { X = value1; r = gr - 2*NKROW - B_; }
  const float4* src = (const float4*)(X + (size_t)r * E_) + i * 8;
  float4 v[8];
  #pragma unroll
  for (int j = 0; j < 8; j++) v[j] = src[j];
  __syncthreads();
  uint4 o[4];
  #pragma unroll
  for (int j = 0; j < 4; j++){
    o[j].x = pack_bf2(v[2*j].x,   v[2*j].y);
    o[j].y = pack_bf2(v[2*j].z,   v[2*j].w);
    o[j].z = pack_bf2(v[2*j+1].x, v[2*j+1].y);
    o[j].w = pack_bf2(v[2*j+1].z, v[2*j+1].w);
  }
  uint4* dst = (uint4*)((u16*)X + (size_t)r * 2048) + i * 4;
  #pragma unroll
  for (int j = 0; j < 4; j++) dst[j] = o[j];
}

// ---------------------------------------------------------------------------
// Kernel 0: convert+transpose the 4 weight matrices to bf16 [col][k].
// ---------------------------------------------------------------------------
__global__ __launch_bounds__(256) void wconv_kernel(
    const float* __restrict__ Wq, const float* __restrict__ Wk,
    const float* __restrict__ Wv1, const float* __restrict__ Wv2,
    u16* __restrict__ Wt)
{
  __shared__ u16 tile[64][72];
  const float* W = (blockIdx.z == 0) ? Wq : (blockIdx.z == 1) ? Wk
                 : (blockIdx.z == 2) ? Wv1 : Wv2;
  u16* out = Wt + (size_t)blockIdx.z * (E_ * E_);
  int k0 = blockIdx.x * 64, c0 = blockIdx.y * 64;
  int tx = threadIdx.x & 63, ty = threadIdx.x >> 6;
  #pragma unroll
  for (int i = 0; i < 16; i++){
    int k = ty * 16 + i;
    tile[k][tx] = f2bf(W[(size_t)(k0 + k) * E_ + c0 + tx]);
  }
  __syncthreads();
  #pragma unroll
  for (int i = 0; i < 16; i++){
    int c = ty * 16 + i;
    out[(size_t)(c0 + c) * E_ + k0 + tx] = tile[tx][c];
  }
}

// ---------------------------------------------------------------------------
// Kernel 1: fused GEMM + bias + celu + group-norm. 128x128 tile, BK=64,
// 4 waves (2x2), 4x4 16x16x32 bf16 frags (64 AGPR). Both operands bf16 via
// global_load_lds(16B). LDS rows = 128B = 8 chunks of 16B, stored with XOR
// swizzle slot = chunk ^ (row&7) => conflict-free ds_read_b128 frag reads.
// k/v2 outputs stored head-major [b*8+h][m][128] for attn's contiguous reads.
// ---------------------------------------------------------------------------
__global__ __launch_bounds__(256) void proj_kernel(
    const u16* __restrict__ xq_, const u16* __restrict__ xk_,
    const u16* __restrict__ xv1_, const u16* __restrict__ xv2_,
    const float* __restrict__ bq, const float* __restrict__ gqw, const float* __restrict__ gqb,
    const float* __restrict__ bk, const float* __restrict__ gkw, const float* __restrict__ gkb,
    const float* __restrict__ bv1, const float* __restrict__ gv1w, const float* __restrict__ gv1b,
    const float* __restrict__ bv2, const float* __restrict__ gv2w, const float* __restrict__ gv2b,
    const u16* __restrict__ Wt,
    u16* __restrict__ qout, u16* __restrict__ khead,
    u16* __restrict__ v1out, u16* __restrict__ v2head)
{
  __shared__ __align__(16) u16 a_lds[128 * 64];   // 16 KB
  __shared__ __align__(16) u16 b_lds[128 * 64];   // 16 KB
  __shared__ float s_sum[256];
  __shared__ float s_sq[256];

  const int tid = threadIdx.x;
  const int w = tid >> 6, lane = tid & 63, qd = lane >> 4, lr = lane & 15;
  const int rh = w >> 1, ch = w & 1;

  const int mtb = blockIdx.y;
  const u16* X; const float *bias, *gw, *gb; u16* outp; int row0, matsel, hm;
  if (mtb < 392)      { X = xk_;  bias = bk;  gw = gkw;  gb = gkb;  outp = khead;  row0 = mtb*128;        matsel = 1; hm = 1; }
  else if (mtb < 784) { X = xv2_; bias = bv2; gw = gv2w; gb = gv2b; outp = v2head; row0 = (mtb-392)*128;  matsel = 3; hm = 1; }
  else if (mtb < 786) { X = xq_;  bias = bq;  gw = gqw;  gb = gqb;  outp = qout;   row0 = (mtb-784)*128;  matsel = 0; hm = 0; }
  else                { X = xv1_; bias = bv1; gw = gv1w; gb = gv1b; outp = v1out;  row0 = (mtb-786)*128;  matsel = 2; hm = 0; }
  const int hsel = blockIdx.x, col0 = hsel * 128;

  // staging lane constants: lane l -> sub-row sr=l>>3, slot sl=l&7,
  // source chunk = sl ^ sr  (so LDS[row][slot] = chunk slot^(row&7))
  const int sl = lane & 7, sr = lane >> 3, swc = sl ^ sr;
  const u16* aptr = X + (size_t)(row0 + w*32 + sr) * 2048 + swc * 8;   // in-place rows: stride 2048 u16
  const u16* bptr = Wt + (size_t)matsel * (E_*E_) + (size_t)(col0 + w*32 + sr) * E_ + swc * 8;

  floatx4 acc[4][4];
  #pragma unroll
  for (int i = 0; i < 4; i++)
    #pragma unroll
    for (int j = 0; j < 4; j++){
      floatx4 z = {0.f, 0.f, 0.f, 0.f};
      acc[i][j] = z;
    }

  for (int kt = 0; kt < 16; kt++){
    __syncthreads();
    #pragma unroll
    for (int c = 0; c < 4; c++)
      gl_lds16(aptr + (size_t)c*8*2048 + kt*64, &a_lds[(w*32 + c*8)*64]);
    #pragma unroll
    for (int c = 0; c < 4; c++)
      gl_lds16(bptr + (size_t)c*8*E_ + kt*64, &b_lds[(w*32 + c*8)*64]);
    __syncthreads();
    #pragma unroll
    for (int ks = 0; ks < 2; ks++){
      const int slot = ((ks*4 + qd) ^ (lr & 7)) * 8;
      short8 afr[4], bfr[4];
      #pragma unroll
      for (int m2 = 0; m2 < 4; m2++)
        afr[m2] = *(const short8*)&a_lds[(rh*64 + m2*16 + lr)*64 + slot];
      #pragma unroll
      for (int nt = 0; nt < 4; nt++)
        bfr[nt] = *(const short8*)&b_lds[(ch*64 + nt*16 + lr)*64 + slot];
      #pragma unroll
      for (int m2 = 0; m2 < 4; m2++)
        #pragma unroll
        for (int nt = 0; nt < 4; nt++)
          acc[m2][nt] = __builtin_amdgcn_mfma_f32_16x16x32_bf16(afr[m2], bfr[nt], acc[m2][nt], 0, 0, 0);
    }
  }

  // Epilogue: bias + celu, row mean/var over the 128-col group (two 64-col
  // wave-halves combined through LDS), normalize, store.
  float biasv[4], gwv[4], gbv[4];
  #pragma unroll
  for (int nt = 0; nt < 4; nt++){
    int c = col0 + ch*64 + nt*16 + lr;
    biasv[nt] = bias[c]; gwv[nt] = gw[c]; gbv[nt] = gb[c];
  }
  #pragma unroll
  for (int m2 = 0; m2 < 4; m2++){
    #pragma unroll
    for (int r = 0; r < 4; r++){
      float s = 0.f, s2 = 0.f;
      #pragma unroll
      for (int nt = 0; nt < 4; nt++){
        float x = acc[m2][nt][r] + biasv[nt];
        x = (x > 0.f) ? x : 1.3f * expm1f(x * (1.0f / 1.3f));
        acc[m2][nt][r] = x;
        s += x; s2 += x * x;
      }
      #pragma unroll
      for (int off = 1; off < 16; off <<= 1){
        s  += __shfl_xor(s,  off, 64);
        s2 += __shfl_xor(s2, off, 64);
      }
      if (lr == 0){
        int row = rh*64 + m2*16 + qd*4 + r;
        s_sum[row*2 + ch] = s;
        s_sq [row*2 + ch] = s2;
      }
    }
  }
  __syncthreads();
  #pragma unroll
  for (int m2 = 0; m2 < 4; m2++){
    #pragma unroll
    for (int r = 0; r < 4; r++){
      int row = rh*64 + m2*16 + qd*4 + r;
      float s  = s_sum[row*2] + s_sum[row*2 + 1];
      float s2 = s_sq [row*2] + s_sq [row*2 + 1];
      float mean = s * 0.0078125f;
      float var  = s2 * 0.0078125f - mean * mean;
      float rstd = rsqrtf(var + 1e-5f);
      u32 rg = row0 + row;
      size_t base;
      if (hm){
        u32 bi = (u32)(((u64)rg * 171197ull) >> 25);   // exact rg/196 for rg<186413
        u32 m  = rg - bi * 196u;
        base = ((size_t)(bi*H_ + hsel)*M_ + m) * DH_ + ch*64;
      } else {
        base = (size_t)rg * E_ + col0 + ch*64;
      }
      #pragma unroll
      for (int nt = 0; nt < 4; nt++)
        outp[base + nt*16 + lr] = f2bf((acc[m2][nt][r] - mean) * rstd * gwv[nt] + gbv[nt]);
    }
  }
}

// ---------------------------------------------------------------------------
// Kernel 2: per-(b,h) attention. khead/v2head are head-major => contiguous
// 256B rows. hidden = relu(khead @ (diag(q)Wb) + bb) via MFMA, never
// materialized; logits + masked hidden-sums in-register; masked softmax;
// vectorized v2 pooling; sigmoid channel gate.
// ---------------------------------------------------------------------------
__global__ __launch_bounds__(256) void attn_kernel(
    const u16* __restrict__ qproj, const u16* __restrict__ khead,
    const u16* __restrict__ v1proj, const u16* __restrict__ v2head,
    const int* __restrict__ mask,
    const float* __restrict__ Wb, const float* __restrict__ bb,
    const float* __restrict__ Ws, const float* __restrict__ bs,
    const float* __restrict__ Wc, const float* __restrict__ bc,
    float* __restrict__ outp)
{
  __shared__ u16 wbt[64 * 136];      // B' = diag(q)*Wb, [n][k], stride 136
  __shared__ float qv[128];
  __shared__ float mrow[208];
  __shared__ float logitv[208];
  __shared__ float hsum_l[4][64];
  __shared__ float wexpv[208];
  __shared__ float poolv[64];
  __shared__ float v2acc[4][128];
  __shared__ float red[8];

  const int tid = threadIdx.x;
  const int w = tid >> 6, lane = tid & 63, qd = lane >> 4, lr = lane & 15;
  const int b = blockIdx.y, h = blockIdx.x;

  const u16* kbase  = khead  + (size_t)(b*H_ + h) * (M_*DH_);
  const u16* v2base = v2head + (size_t)(b*H_ + h) * (M_*DH_);

  if (tid < 128) qv[tid] = bf2f(qproj[(size_t)b * E_ + h * DH_ + tid]);
  if (tid < 208) mrow[tid] = (tid < M_) ? (float)mask[b * M_ + tid] : 0.f;
  __syncthreads();

  {
    int n = tid & 63, kb = (tid >> 6) * 32;
    #pragma unroll
    for (int kk = 0; kk < 32; kk++)
      wbt[n * 136 + kb + kk] = f2bf(qv[kb + kk] * Wb[(kb + kk) * MID_ + n]);
  }
  __syncthreads();

  float wsv[4], bbv[4];
  #pragma unroll
  for (int nt = 0; nt < 4; nt++){ wsv[nt] = Ws[nt * 16 + lr]; bbv[nt] = bb[nt * 16 + lr]; }
  const float bsv = bs[0];
  float hs[4] = {0, 0, 0, 0};

  for (int mt = w; mt < 13; mt += 4){
    int mrow_g = mt * 16 + lr;
    int mcl = (mrow_g < M_) ? mrow_g : (M_ - 1);
    const u16* arow = kbase + (size_t)mcl * DH_;
    floatx4 hacc[4];
    #pragma unroll
    for (int nt = 0; nt < 4; nt++){ floatx4 z = {0.f, 0.f, 0.f, 0.f}; hacc[nt] = z; }
    #pragma unroll
    for (int kc = 0; kc < 4; kc++){
      short8 afr = *(const short8*)(arow + kc * 32 + qd * 8);
      #pragma unroll
      for (int nt = 0; nt < 4; nt++){
        short8 bfr = *(const short8*)&wbt[(nt * 16 + lr) * 136 + kc * 32 + qd * 8];
        hacc[nt] = __builtin_amdgcn_mfma_f32_16x16x32_bf16(afr, bfr, hacc[nt], 0, 0, 0);
      }
    }
    float lp[4] = {0, 0, 0, 0};
    #pragma unroll
    for (int nt = 0; nt < 4; nt++){
      #pragma unroll
      for (int r = 0; r < 4; r++){
        float hv = hacc[nt][r] + bbv[nt];
        hv = fmaxf(hv, 0.f);
        lp[r] += hv * wsv[nt];
        hs[nt] += mrow[mt * 16 + qd * 4 + r] * hv;
      }
    }
    #pragma unroll
    for (int r = 0; r < 4; r++){
      float a = lp[r];
      #pragma unroll
      for (int off = 1; off < 16; off <<= 1) a += __shfl_xor(a, off, 64);
      if (lr == 0) logitv[mt * 16 + qd * 4 + r] = a + bsv;
    }
  }
  #pragma unroll
  for (int nt = 0; nt < 4; nt++){
    hs[nt] += __shfl_xor(hs[nt], 16, 64);
    hs[nt] += __shfl_xor(hs[nt], 32, 64);
  }
  if (lane < 16){
    #pragma unroll
    for (int nt = 0; nt < 4; nt++) hsum_l[w][nt * 16 + lane] = hs[nt];
  }
  __syncthreads();

  if (w == 0){
    float s = 0.f;
    for (int m = lane; m < M_; m += 64) s += mrow[m];
    #pragma unroll
    for (int off = 1; off < 64; off <<= 1) s += __shfl_xor(s, off, 64);
    if (lane == 0) red[0] = s;
  } else if (w == 1){
    float mx = -1e30f;
    for (int m = lane; m < M_; m += 64) if (mrow[m] > 0.5f) mx = fmaxf(mx, logitv[m]);
    #pragma unroll
    for (int off = 1; off < 64; off <<= 1) mx = fmaxf(mx, __shfl_xor(mx, off, 64));
    if (lane == 0) red[1] = mx;
  } else if (w == 2){
    poolv[lane & 63] = hsum_l[0][lane & 63] + hsum_l[1][lane & 63]
                     + hsum_l[2][lane & 63] + hsum_l[3][lane & 63];
  }
  __syncthreads();
  const float cnt = red[0], mx = red[1];
  if (tid < 208)
    wexpv[tid] = (tid < M_ && mrow[tid] > 0.5f) ? expf(logitv[tid] - mx) : 0.f;
  __syncthreads();
  if (w == 0){
    float s = 0.f;
    for (int m = lane; m < M_; m += 64) s += wexpv[m];
    #pragma unroll
    for (int off = 1; off < 64; off <<= 1) s += __shfl_xor(s, off, 64);
    if (lane == 0) red[2] = s;
  } else if (w == 1){
    poolv[lane & 63] = poolv[lane & 63] / cnt;
  }
  __syncthreads();
  const float S = red[2];

  // v2 pooling: per iter a wave covers rows {it*16 + w*4 + qd}, 16B/lane.
  {
    float ac[8] = {0, 0, 0, 0, 0, 0, 0, 0};
    #pragma unroll
    for (int it = 0; it < 13; it++){
      int m = it * 16 + w * 4 + qd;
      if (m < M_){
        float we = wexpv[m];
        uint4 u = *(const uint4*)(v2base + (size_t)m * DH_ + lr * 8);
        ac[0] += we * bf2f((u16)(u.x & 0xffff));
        ac[1] += we * bf2f((u16)(u.x >> 16));
        ac[2] += we * bf2f((u16)(u.y & 0xffff));
        ac[3] += we * bf2f((u16)(u.y >> 16));
        ac[4] += we * bf2f((u16)(u.z & 0xffff));
        ac[5] += we * bf2f((u16)(u.z >> 16));
        ac[6] += we * bf2f((u16)(u.w & 0xffff));
        ac[7] += we * bf2f((u16)(u.w >> 16));
      }
    }
    #pragma unroll
    for (int j = 0; j < 8; j++){
      ac[j] += __shfl_xor(ac[j], 16, 64);
      ac[j] += __shfl_xor(ac[j], 32, 64);
    }
    if (qd == 0){
      #pragma unroll
      for (int j = 0; j < 8; j++) v2acc[w][lr * 8 + j] = ac[j];
    }
  }
  __syncthreads();

  if (tid < 128){
    float a = 0.f;
    #pragma unroll 8
    for (int j = 0; j < 64; j++) a += poolv[j] * Wc[j * DH_ + tid];
    float acv = 1.f / (1.f + expf(-(a + bc[tid])));
    float vp = (v2acc[0][tid] + v2acc[1][tid] + v2acc[2][tid] + v2acc[3][tid]) / S;
    float o = bf2f(v1proj[(size_t)b * E_ + h * DH_ + tid]) * vp * acv;
    outp[(size_t)b * E_ + h * DH_ + tid] = o;
  }
}

// ---------------------------------------------------------------------------
extern "C" void kernel_launch(void* const* d_in, const int* in_sizes, int n_in,
                              void* d_out, int out_size, void* d_ws, size_t ws_size,
                              hipStream_t stream)
{
  float* query  = (float*)d_in[0];
  float* key    = (float*)d_in[1];
  const int* mask = (const int*)d_in[2];
  float* value1 = (float*)d_in[3];
  float* value2 = (float*)d_in[4];
  const float* Wq  = (const float*)d_in[5];
  const float* bq  = (const float*)d_in[6];
  const float* gqw = (const float*)d_in[7];
  const float* gqb = (const float*)d_in[8];
  const float* Wk  = (const float*)d_in[9];
  const float* bk  = (const float*)d_in[10];
  const float* gkw = (const float*)d_in[11];
  const float* gkb = (const float*)d_in[12];
  const float* Wv1 = (const float*)d_in[13];
  const float* bv1 = (const float*)d_in[14];
  const float* gv1w= (const float*)d_in[15];
  const float* gv1b= (const float*)d_in[16];
  const float* Wv2 = (const float*)d_in[17];
  const float* bv2 = (const float*)d_in[18];
  const float* gv2w= (const float*)d_in[19];
  const float* gv2b= (const float*)d_in[20];
  const float* Wb  = (const float*)d_in[21];
  const float* bb  = (const float*)d_in[22];
  const float* Ws  = (const float*)d_in[23];
  const float* bs  = (const float*)d_in[24];
  const float* Wc  = (const float*)d_in[25];
  const float* bc  = (const float*)d_in[26];

  const size_t NHD = (size_t)B_ * H_ * M_ * DH_;   // 51,380,224
  u16* khead  = (u16*)d_ws;
  u16* v2head = khead  + NHD;
  u16* qout   = v2head + NHD;
  u16* v1out  = qout   + (size_t)B_ * E_;
  u16* Wt     = v1out  + (size_t)B_ * E_;          // 4 * 1024*1024 bf16

  xconv_kernel<<<(2*NKROW + 2*B_)/8, 256, 0, stream>>>(key, value2, query, value1);

  dim3 g0(16, 16, 4);
  wconv_kernel<<<g0, 256, 0, stream>>>(Wq, Wk, Wv1, Wv2, Wt);

  dim3 g1(8, 788);
  proj_kernel<<<g1, 256, 0, stream>>>(
      (const u16*)query, (const u16*)key, (const u16*)value1, (const u16*)value2,
      bq, gqw, gqb, bk, gkw, gkb, bv1, gv1w, gv1b, bv2, gv2w, gv2b,
      Wt, qout, khead, v1out, v2head);

  dim3 g2(H_, B_);
  attn_kernel<<<g2, 256, 0, stream>>>(qout, khead, v1out, v2head, mask,
      Wb, bb, Ws, bs, Wc, bc, (float*)d_out);
}

// Round 4
// 924.008 us; speedup vs baseline: 1.1038x; 1.1038x over previous
//
#include <hip/hip_runtime.h>

typedef unsigned short u16;
typedef unsigned int u32;
typedef unsigned long long u64;
typedef __attribute__((ext_vector_type(8))) short short8;
typedef __attribute__((ext_vector_type(4))) float floatx4;

#define E_ 1024
#define B_ 256
#define M_ 196
#define H_ 8
#define DH_ 128
#define MID_ 64
#define NKROW 50176   // B_*M_

__device__ __forceinline__ u16 f2bf(float f){
  union { float f; u32 u; } v; v.f = f;
  return (u16)((v.u + (((v.u >> 16) & 1u) + 0x7fffu)) >> 16);
}
__device__ __forceinline__ float bf2f(u16 h){
  union { u32 u; float f; } v; v.u = ((u32)h) << 16;
  return v.f;
}
// pack two floats to bf16x2 (low = a, high = b)
__device__ __forceinline__ u32 pack_bf2(float a, float b){
  u32 ua = __float_as_uint(a) + 0x8000u;
  u32 ub = __float_as_uint(b) + 0x8000u;
  return __builtin_amdgcn_perm(ub, ua, 0x07060302);
}
// async global->LDS, 16B/lane; LDS dest = wave-uniform base + lane*16
__device__ __forceinline__ void gl_lds16(const void* g, void* l){
  __builtin_amdgcn_global_load_lds(
      (const __attribute__((address_space(1))) u32*)g,
      (__attribute__((address_space(3))) u32*)l, 16, 0, 0);
}
__device__ __forceinline__ float celu_f(float x){
  // celu(x, 1.3) = x>0 ? x : 1.3*(exp(x/1.3)-1), fast v_exp path
  float xn = 1.3f * (__expf(x * 0.76923076923f) - 1.0f);
  return x > 0.f ? x : xn;
}

// ---------------------------------------------------------------------------
// Kernel X: in-place fp32 -> bf16, fully coalesced. 8 rows/block, 32 thr/row.
// Read all 8 float4 (lane-contiguous 512B per inst), barrier, write packed
// uint2 (lane-contiguous 256B per inst) into the row's front half.
// ---------------------------------------------------------------------------
__global__ __launch_bounds__(256) void xconv_kernel(
    float* __restrict__ key, float* __restrict__ value2,
    float* __restrict__ query, float* __restrict__ value1)
{
  int gr = blockIdx.x * 8 + (threadIdx.x >> 5);
  int i  = threadIdx.x & 31;
  float* X; int r;
  if (gr < NKROW)               { X = key;    r = gr; }
  else if (gr < 2*NKROW)        { X = value2; r = gr - NKROW; }
  else if (gr < 2*NKROW + B_)   { X = query;  r = gr - 2*NKROW; }
  else                          { X = value1; r = gr - 2*NKROW - B_; }
  const float4* src = (const float4*)(X + (size_t)r * E_);
  float4 v[8];
  #pragma unroll
  for (int j = 0; j < 8; j++) v[j] = src[j * 32 + i];
  __syncthreads();
  uint2* dst = (uint2*)((u16*)X + (size_t)r * 2048);
  #pragma unroll
  for (int j = 0; j < 8; j++){
    uint2 o;
    o.x = pack_bf2(v[j].x, v[j].y);
    o.y = pack_bf2(v[j].z, v[j].w);
    dst[j * 32 + i] = o;
  }
}

// ---------------------------------------------------------------------------
// Kernel 0: convert+transpose the 4 weight matrices to bf16 [col][k].
// ---------------------------------------------------------------------------
__global__ __launch_bounds__(256) void wconv_kernel(
    const float* __restrict__ Wq, const float* __restrict__ Wk,
    const float* __restrict__ Wv1, const float* __restrict__ Wv2,
    u16* __restrict__ Wt)
{
  __shared__ u16 tile[64][72];
  const float* W = (blockIdx.z == 0) ? Wq : (blockIdx.z == 1) ? Wk
                 : (blockIdx.z == 2) ? Wv1 : Wv2;
  u16* out = Wt + (size_t)blockIdx.z * (E_ * E_);
  int k0 = blockIdx.x * 64, c0 = blockIdx.y * 64;
  int tx = threadIdx.x & 63, ty = threadIdx.x >> 6;
  #pragma unroll
  for (int i = 0; i < 16; i++){
    int k = ty * 16 + i;
    tile[k][tx] = f2bf(W[(size_t)(k0 + k) * E_ + c0 + tx]);
  }
  __syncthreads();
  #pragma unroll
  for (int i = 0; i < 16; i++){
    int c = ty * 16 + i;
    out[(size_t)(c0 + c) * E_ + k0 + tx] = tile[tx][c];
  }
}

// ---------------------------------------------------------------------------
// Kernel 1: fused GEMM + bias + celu + group-norm. 256x256 tile, BK=32,
// DOUBLE-BUFFERED LDS (2x32KB), 512 threads = 8 waves (wave grid 4 rows x
// 2 cols: each wave 64 rows x 128 cols = one full groupnorm head-group =>
// groupnorm entirely in-wave). 4x8 frags of 16x16x32 bf16 (128 AGPR).
// Staging via global_load_lds(16B) with XOR slot swizzle (slot = qd^(row&3))
// => bijective granule coverage, zero bank conflicts (verified R3).
// Tile economics: staged bytes 1.6 GB vs 3.2 GB at 128^2 — staging-rate was
// the measured R3 wall (~10.7 B/cyc/CU).
// ---------------------------------------------------------------------------
__global__ __launch_bounds__(512, 2) void proj_kernel(
    const u16* __restrict__ xq_, const u16* __restrict__ xk_,
    const u16* __restrict__ xv1_, const u16* __restrict__ xv2_,
    const float* __restrict__ bq, const float* __restrict__ gqw, const float* __restrict__ gqb,
    const float* __restrict__ bk, const float* __restrict__ gkw, const float* __restrict__ gkb,
    const float* __restrict__ bv1, const float* __restrict__ gv1w, const float* __restrict__ gv1b,
    const float* __restrict__ bv2, const float* __restrict__ gv2w, const float* __restrict__ gv2b,
    const u16* __restrict__ Wt,
    u16* __restrict__ qout, u16* __restrict__ khead,
    u16* __restrict__ v1out, u16* __restrict__ v2head)
{
  __shared__ __align__(16) u16 a_lds[2][256 * 32];   // 2 x 16 KB
  __shared__ __align__(16) u16 b_lds[2][256 * 32];   // 2 x 16 KB

  const int tid = threadIdx.x;
  const int w = tid >> 6, lane = tid & 63, qd = lane >> 4, lr = lane & 15;
  const int wm = w & 3, wn = w >> 2;      // wave grid: 4 row-quads x 2 col-halves

  const int mtb = blockIdx.x;
  const u16* X; const float *bias, *gw, *gb; u16* outp; int row0, matsel, hm;
  if (mtb < 196)      { X = xk_;  bias = bk;  gw = gkw;  gb = gkb;  outp = khead;  row0 = mtb*256;        matsel = 1; hm = 1; }
  else if (mtb < 392) { X = xv2_; bias = bv2; gw = gv2w; gb = gv2b; outp = v2head; row0 = (mtb-196)*256;  matsel = 3; hm = 1; }
  else if (mtb == 392){ X = xq_;  bias = bq;  gw = gqw;  gb = gqb;  outp = qout;   row0 = 0;              matsel = 0; hm = 0; }
  else                { X = xv1_; bias = bv1; gw = gv1w; gb = gv1b; outp = v1out;  row0 = 0;              matsel = 2; hm = 0; }
  const int cp = blockIdx.y, col0 = cp * 256;

  // staging lane constants: lane -> sub-row (l>>2), slot (l&3), src chunk = slot^(row&3)
  const int srow = lane >> 2, sslot = lane & 3, sswz = sslot ^ (srow & 3);
  // A rows (in-place bf16, row stride 2048 u16); wave w stages rows (w*2+c)*16..
  const u16* aptr0 = X + (size_t)(row0 + (w*2    )*16 + srow) * 2048 + sswz * 8;
  const u16* aptr1 = X + (size_t)(row0 + (w*2 + 1)*16 + srow) * 2048 + sswz * 8;
  // B cols as rows (Wt [col][k], stride 1024 u16)
  const u16* wbase = Wt + (size_t)matsel * (E_*E_);
  const u16* bptr0 = wbase + (size_t)(col0 + (w*2    )*16 + srow) * E_ + sswz * 8;
  const u16* bptr1 = wbase + (size_t)(col0 + (w*2 + 1)*16 + srow) * E_ + sswz * 8;

  floatx4 acc[4][8];
  #pragma unroll
  for (int i = 0; i < 4; i++)
    #pragma unroll
    for (int j = 0; j < 8; j++){
      floatx4 z = {0.f, 0.f, 0.f, 0.f};
      acc[i][j] = z;
    }

  // prologue: stage kt=0 into buffer 0
  gl_lds16(aptr0, &a_lds[0][(w*2    )*16*32]);
  gl_lds16(aptr1, &a_lds[0][(w*2 + 1)*16*32]);
  gl_lds16(bptr0, &b_lds[0][(w*2    )*16*32]);
  gl_lds16(bptr1, &b_lds[0][(w*2 + 1)*16*32]);
  __syncthreads();

  const int fslot = (qd ^ (lr & 3)) * 8;   // frag k-chunk slot after swizzle
  for (int kt = 0; kt < 32; kt++){
    const int cur = kt & 1, nxt = cur ^ 1;
    if (kt < 31){
      const int ko = (kt + 1) * 32;
      gl_lds16(aptr0 + ko, &a_lds[nxt][(w*2    )*16*32]);
      gl_lds16(aptr1 + ko, &a_lds[nxt][(w*2 + 1)*16*32]);
      gl_lds16(bptr0 + ko, &b_lds[nxt][(w*2    )*16*32]);
      gl_lds16(bptr1 + ko, &b_lds[nxt][(w*2 + 1)*16*32]);
    }
    short8 afr[4], bfr[8];
    #pragma unroll
    for (int m2 = 0; m2 < 4; m2++)
      afr[m2] = *(const short8*)&a_lds[cur][(wm*64 + m2*16 + lr)*32 + fslot];
    #pragma unroll
    for (int nt = 0; nt < 8; nt++)
      bfr[nt] = *(const short8*)&b_lds[cur][(wn*128 + nt*16 + lr)*32 + fslot];
    #pragma unroll
    for (int m2 = 0; m2 < 4; m2++)
      #pragma unroll
      for (int nt = 0; nt < 8; nt++)
        acc[m2][nt] = __builtin_amdgcn_mfma_f32_16x16x32_bf16(afr[m2], bfr[nt], acc[m2][nt], 0, 0, 0);
    __syncthreads();   // kt+1 staging drained; everyone done reading buf[cur]
  }

  // Epilogue: bias + celu, groupnorm over this wave's 128-col head group
  // (in-register + 16-lane shuffles only), store bf16 (head-major for k/v2).
  float biasv[8], gwv[8], gbv[8];
  #pragma unroll
  for (int nt = 0; nt < 8; nt++){
    int c = col0 + wn*128 + nt*16 + lr;
    biasv[nt] = bias[c]; gwv[nt] = gw[c]; gbv[nt] = gb[c];
  }
  const int head = cp*2 + wn;
  #pragma unroll
  for (int m2 = 0; m2 < 4; m2++){
    #pragma unroll
    for (int r = 0; r < 4; r++){
      float s = 0.f, s2 = 0.f;
      #pragma unroll
      for (int nt = 0; nt < 8; nt++){
        float x = celu_f(acc[m2][nt][r] + biasv[nt]);
        acc[m2][nt][r] = x;
        s += x; s2 += x * x;
      }
      #pragma unroll
      for (int off = 1; off < 16; off <<= 1){
        s  += __shfl_xor(s,  off, 64);
        s2 += __shfl_xor(s2, off, 64);
      }
      float mean = s * 0.0078125f;
      float var  = s2 * 0.0078125f - mean * mean;
      float rstd = rsqrtf(var + 1e-5f);
      u32 rg = row0 + wm*64 + m2*16 + qd*4 + r;
      size_t base;
      if (hm){
        u32 bi = (u32)(((u64)rg * 171197ull) >> 25);   // exact rg/196 (rg < 186413)
        u32 m  = rg - bi * 196u;
        base = ((size_t)(bi*H_ + head)*M_ + m) * DH_;
      } else {
        base = (size_t)rg * E_ + head * DH_;
      }
      #pragma unroll
      for (int nt = 0; nt < 8; nt++)
        outp[base + nt*16 + lr] = f2bf((acc[m2][nt][r] - mean) * rstd * gwv[nt] + gbv[nt]);
    }
  }
}

// ---------------------------------------------------------------------------
// Kernel 2: per-(b,h) attention. khead/v2head head-major => contiguous 256B
// rows. hidden = relu(khead @ (diag(q)Wb) + bb) via MFMA, never materialized.
// ---------------------------------------------------------------------------
__global__ __launch_bounds__(256) void attn_kernel(
    const u16* __restrict__ qproj, const u16* __restrict__ khead,
    const u16* __restrict__ v1proj, const u16* __restrict__ v2head,
    const int* __restrict__ mask,
    const float* __restrict__ Wb, const float* __restrict__ bb,
    const float* __restrict__ Ws, const float* __restrict__ bs,
    const float* __restrict__ Wc, const float* __restrict__ bc,
    float* __restrict__ outp)
{
  __shared__ u16 wbt[64 * 136];      // B' = diag(q)*Wb, [n][k], stride 136
  __shared__ float qv[128];
  __shared__ float mrow[208];
  __shared__ float logitv[208];
  __shared__ float hsum_l[4][64];
  __shared__ float wexpv[208];
  __shared__ float poolv[64];
  __shared__ float v2acc[4][128];
  __shared__ float wc2[2][128];
  __shared__ float red[8];

  const int tid = threadIdx.x;
  const int w = tid >> 6, lane = tid & 63, qd = lane >> 4, lr = lane & 15;
  const int b = blockIdx.y, h = blockIdx.x;

  const u16* kbase  = khead  + (size_t)(b*H_ + h) * (M_*DH_);
  const u16* v2base = v2head + (size_t)(b*H_ + h) * (M_*DH_);

  if (tid < 128) qv[tid] = bf2f(qproj[(size_t)b * E_ + h * DH_ + tid]);
  if (tid < 208) mrow[tid] = (tid < M_) ? (float)mask[b * M_ + tid] : 0.f;
  __syncthreads();

  {
    int n = tid & 63, kb = (tid >> 6) * 32;
    #pragma unroll
    for (int kk = 0; kk < 32; kk++)
      wbt[n * 136 + kb + kk] = f2bf(qv[kb + kk] * Wb[(kb + kk) * MID_ + n]);
  }
  __syncthreads();

  float wsv[4], bbv[4];
  #pragma unroll
  for (int nt = 0; nt < 4; nt++){ wsv[nt] = Ws[nt * 16 + lr]; bbv[nt] = bb[nt * 16 + lr]; }
  const float bsv = bs[0];
  float hs[4] = {0, 0, 0, 0};

  for (int mt = w; mt < 13; mt += 4){
    int mrow_g = mt * 16 + lr;
    int mcl = (mrow_g < M_) ? mrow_g : (M_ - 1);
    const u16* arow = kbase + (size_t)mcl * DH_;
    floatx4 hacc[4];
    #pragma unroll
    for (int nt = 0; nt < 4; nt++){ floatx4 z = {0.f, 0.f, 0.f, 0.f}; hacc[nt] = z; }
    #pragma unroll
    for (int kc = 0; kc < 4; kc++){
      short8 afr = *(const short8*)(arow + kc * 32 + qd * 8);
      #pragma unroll
      for (int nt = 0; nt < 4; nt++){
        short8 bfr = *(const short8*)&wbt[(nt * 16 + lr) * 136 + kc * 32 + qd * 8];
        hacc[nt] = __builtin_amdgcn_mfma_f32_16x16x32_bf16(afr, bfr, hacc[nt], 0, 0, 0);
      }
    }
    float lp[4] = {0, 0, 0, 0};
    #pragma unroll
    for (int nt = 0; nt < 4; nt++){
      #pragma unroll
      for (int r = 0; r < 4; r++){
        float hv = hacc[nt][r] + bbv[nt];
        hv = fmaxf(hv, 0.f);
        lp[r] += hv * wsv[nt];
        hs[nt] += mrow[mt * 16 + qd * 4 + r] * hv;
      }
    }
    #pragma unroll
    for (int r = 0; r < 4; r++){
      float a = lp[r];
      #pragma unroll
      for (int off = 1; off < 16; off <<= 1) a += __shfl_xor(a, off, 64);
      if (lr == 0) logitv[mt * 16 + qd * 4 + r] = a + bsv;
    }
  }
  #pragma unroll
  for (int nt = 0; nt < 4; nt++){
    hs[nt] += __shfl_xor(hs[nt], 16, 64);
    hs[nt] += __shfl_xor(hs[nt], 32, 64);
  }
  if (lane < 16){
    #pragma unroll
    for (int nt = 0; nt < 4; nt++) hsum_l[w][nt * 16 + lane] = hs[nt];
  }
  __syncthreads();

  if (w == 0){
    float s = 0.f;
    for (int m = lane; m < M_; m += 64) s += mrow[m];
    #pragma unroll
    for (int off = 1; off < 64; off <<= 1) s += __shfl_xor(s, off, 64);
    if (lane == 0) red[0] = s;
  } else if (w == 1){
    float mx = -1e30f;
    for (int m = lane; m < M_; m += 64) if (mrow[m] > 0.5f) mx = fmaxf(mx, logitv[m]);
    #pragma unroll
    for (int off = 1; off < 64; off <<= 1) mx = fmaxf(mx, __shfl_xor(mx, off, 64));
    if (lane == 0) red[1] = mx;
  } else if (w == 2){
    poolv[lane & 63] = hsum_l[0][lane & 63] + hsum_l[1][lane & 63]
                     + hsum_l[2][lane & 63] + hsum_l[3][lane & 63];
  }
  __syncthreads();
  const float cnt = red[0], mx = red[1];
  if (tid < 208)
    wexpv[tid] = (tid < M_ && mrow[tid] > 0.5f) ? __expf(logitv[tid] - mx) : 0.f;
  __syncthreads();
  if (w == 0){
    float s = 0.f;
    for (int m = lane; m < M_; m += 64) s += wexpv[m];
    #pragma unroll
    for (int off = 1; off < 64; off <<= 1) s += __shfl_xor(s, off, 64);
    if (lane == 0) red[2] = s;
  } else if (w == 1){
    poolv[lane & 63] = poolv[lane & 63] / cnt;
  }
  __syncthreads();
  const float S = red[2];

  // v2 pooling: per iter a wave covers rows {it*16 + w*4 + qd}, 16B/lane.
  {
    float ac[8] = {0, 0, 0, 0, 0, 0, 0, 0};
    #pragma unroll
    for (int it = 0; it < 13; it++){
      int m = it * 16 + w * 4 + qd;
      if (m < M_){
        float we = wexpv[m];
        uint4 u = *(const uint4*)(v2base + (size_t)m * DH_ + lr * 8);
        ac[0] += we * bf2f((u16)(u.x & 0xffff));
        ac[1] += we * bf2f((u16)(u.x >> 16));
        ac[2] += we * bf2f((u16)(u.y & 0xffff));
        ac[3] += we * bf2f((u16)(u.y >> 16));
        ac[4] += we * bf2f((u16)(u.z & 0xffff));
        ac[5] += we * bf2f((u16)(u.z >> 16));
        ac[6] += we * bf2f((u16)(u.w & 0xffff));
        ac[7] += we * bf2f((u16)(u.w >> 16));
      }
    }
    #pragma unroll
    for (int j = 0; j < 8; j++){
      ac[j] += __shfl_xor(ac[j], 16, 64);
      ac[j] += __shfl_xor(ac[j], 32, 64);
    }
    if (qd == 0){
      #pragma unroll
      for (int j = 0; j < 8; j++) v2acc[w][lr * 8 + j] = ac[j];
    }
  }
  __syncthreads();

  // channel gate gemv: split the 64-term dot over 2 thread-halves
  {
    int d = tid & 127, jh = tid >> 7;
    float a = 0.f;
    #pragma unroll 8
    for (int j = jh * 32; j < jh * 32 + 32; j++) a += poolv[j] * Wc[j * DH_ + d];
    wc2[jh][d] = a;
  }
  __syncthreads();

  if (tid < 128){
    float a = wc2[0][tid] + wc2[1][tid];
    float acv = 1.f / (1.f + __expf(-(a + bc[tid])));
    float vp = (v2acc[0][tid] + v2acc[1][tid] + v2acc[2][tid] + v2acc[3][tid]) / S;
    float o = bf2f(v1proj[(size_t)b * E_ + h * DH_ + tid]) * vp * acv;
    outp[(size_t)b * E_ + h * DH_ + tid] = o;
  }
}

// ---------------------------------------------------------------------------
extern "C" void kernel_launch(void* const* d_in, const int* in_sizes, int n_in,
                              void* d_out, int out_size, void* d_ws, size_t ws_size,
                              hipStream_t stream)
{
  float* query  = (float*)d_in[0];
  float* key    = (float*)d_in[1];
  const int* mask = (const int*)d_in[2];
  float* value1 = (float*)d_in[3];
  float* value2 = (float*)d_in[4];
  const float* Wq  = (const float*)d_in[5];
  const float* bq  = (const float*)d_in[6];
  const float* gqw = (const float*)d_in[7];
  const float* gqb = (const float*)d_in[8];
  const float* Wk  = (const float*)d_in[9];
  const float* bk  = (const float*)d_in[10];
  const float* gkw = (const float*)d_in[11];
  const float* gkb = (const float*)d_in[12];
  const float* Wv1 = (const float*)d_in[13];
  const float* bv1 = (const float*)d_in[14];
  const float* gv1w= (const float*)d_in[15];
  const float* gv1b= (const float*)d_in[16];
  const float* Wv2 = (const float*)d_in[17];
  const float* bv2 = (const float*)d_in[18];
  const float* gv2w= (const float*)d_in[19];
  const float* gv2b= (const float*)d_in[20];
  const float* Wb  = (const float*)d_in[21];
  const float* bb  = (const float*)d_in[22];
  const float* Ws  = (const float*)d_in[23];
  const float* bs  = (const float*)d_in[24];
  const float* Wc  = (const float*)d_in[25];
  const float* bc  = (const float*)d_in[26];

  const size_t NHD = (size_t)B_ * H_ * M_ * DH_;   // 51,380,224
  u16* khead  = (u16*)d_ws;
  u16* v2head = khead  + NHD;
  u16* qout   = v2head + NHD;
  u16* v1out  = qout   + (size_t)B_ * E_;
  u16* Wt     = v1out  + (size_t)B_ * E_;          // 4 * 1024*1024 bf16

  xconv_kernel<<<(2*NKROW + 2*B_)/8, 256, 0, stream>>>(key, value2, query, value1);

  dim3 g0(16, 16, 4);
  wconv_kernel<<<g0, 256, 0, stream>>>(Wq, Wk, Wv1, Wv2, Wt);

  dim3 g1(394, 4);   // row-panel fast-varying: A streams through L3 per col pass
  proj_kernel<<<g1, 512, 0, stream>>>(
      (const u16*)query, (const u16*)key, (const u16*)value1, (const u16*)value2,
      bq, gqw, gqb, bk, gkw, gkb, bv1, gv1w, gv1b, bv2, gv2w, gv2b,
      Wt, qout, khead, v1out, v2head);

  dim3 g2(H_, B_);
  attn_kernel<<<g2, 256, 0, stream>>>(qout, khead, v1out, v2head, mask,
      Wb, bb, Ws, bs, Wc, bc, (float*)d_out);
}